// Round 8
// baseline (370.806 us; speedup 1.0000x reference)
//
#include <hip/hip_runtime.h>
#include <hip/hip_bf16.h>
#include <stdint.h>

#define HH 128
#define WW 128
#define CC 80
#define HW (HH * WW)
#define BB 32
#define TOPK 100
#define NTHREADS 256
#define SCORE_THR 0.3f
#define NMS_IOU 0.3f
#define BUF 512
#define GG 4
#define PLANE ((size_t)BB * HW)
// smallest uint bit pattern with float > 0.3f  (bits(0.3f)=0x3E99999A)
#define MINT 0x3E99999Bu

// ---------------------------------------------------------------------------
// Kernel A: peak-NMS + per-group channel max/argmax. NO LDS, NO barriers.
// Grid: 32 b x 4 groups x 16 stripes = 2048 blocks (8 blocks/CU), 256 thr.
// Round-8: round-7's vertical-max-first pool (2 shuffles/channel) kept, but
// the rotating A[3][3] array (which the compiler lowered to SCRATCH: round-7
// WRITE_SIZE=237MB, 143us) is replaced by NAMED float4 registers in an
// explicit even/odd 2-slot pipeline with zero copies and zero dynamic
// indexing. While computing the even channel, the odd channel's 3 loads are
// in flight, and vice versa. ~45 VGPR -> true 8 blocks/CU.
// Clamp pad == -inf pad for 3x3 max-pool. Partials PLANAR [G][B*HW].
// ---------------------------------------------------------------------------
__global__ __launch_bounds__(NTHREADS, 8)
void heat_reduce(const float* __restrict__ hm,
                 float* __restrict__ conf_part,
                 unsigned char* __restrict__ cls_part) {
    constexpr int CPG = CC / GG;              // 20 channels per group
    const int stripe = blockIdx.x & 15;
    const int g      = (blockIdx.x >> 4) & 3;
    const int b      = blockIdx.x >> 6;
    const int tid    = threadIdx.x;
    const int c31    = tid & 31;
    const int r      = tid >> 5;              // 0..7 row within stripe
    const int x4     = c31 << 2;              // 0,4,...,124
    const int y      = stripe * 8 + r;
    const int yM     = (y > 0) ? y - 1 : 0;
    const int yP     = (y < HH - 1) ? y + 1 : y;
    const bool leftClamp  = (c31 == 0);
    const bool rightClamp = (c31 == 31);
    const int c0     = g * CPG;

    const float* cbase = hm + (size_t)(b * CC + c0) * HW;
    const uint u0 = (uint)(yM * WW + x4);     // row above (clamped)
    const uint u1 = (uint)(y  * WW + x4);     // center row
    const uint u2 = (uint)(yP * WW + x4);     // row below (clamped)

    float conf[4] = {0.f, 0.f, 0.f, 0.f};
    int   cls[4]  = {c0, c0, c0, c0};

    float4 eA, eB, eC;                        // even-channel slot
    float4 oA, oB, oC;                        // odd-channel slot

#define LOADC(cc, rA, rB, rC)                                   \
    {                                                           \
        const float* cb_ = cbase + (size_t)(cc) * HW;           \
        rA = *(const float4*)(cb_ + u0);                        \
        rB = *(const float4*)(cb_ + u1);                        \
        rC = *(const float4*)(cb_ + u2);                        \
    }

#define CMPC(cc, rA, rB, rC)                                    \
    {                                                           \
        float vx = fmaxf(fmaxf(rA.x, rB.x), rC.x);              \
        float vy = fmaxf(fmaxf(rA.y, rB.y), rC.y);              \
        float vz = fmaxf(fmaxf(rA.z, rB.z), rC.z);              \
        float vw = fmaxf(fmaxf(rA.w, rB.w), rC.w);              \
        float le = __shfl_up(vw, 1, 64);                        \
        float re = __shfl_down(vx, 1, 64);                      \
        if (leftClamp)  le = vx;                                \
        if (rightClamp) re = vw;                                \
        float p0 = fmaxf(fmaxf(le, vx), vy);                    \
        float p1 = fmaxf(fmaxf(vx, vy), vz);                    \
        float p2 = fmaxf(fmaxf(vy, vz), vw);                    \
        float p3 = fmaxf(fmaxf(vz, vw), re);                    \
        const int c_ = c0 + (cc);                               \
        if ((rB.x == p0) && (rB.x > conf[0])) { conf[0] = rB.x; cls[0] = c_; } \
        if ((rB.y == p1) && (rB.y > conf[1])) { conf[1] = rB.y; cls[1] = c_; } \
        if ((rB.z == p2) && (rB.z > conf[2])) { conf[2] = rB.z; cls[2] = c_; } \
        if ((rB.w == p3) && (rB.w > conf[3])) { conf[3] = rB.w; cls[3] = c_; } \
    }

    LOADC(0, eA, eB, eC)
    LOADC(1, oA, oB, oC)
#pragma unroll
    for (int p = 0; p < CPG / 2; ++p) {       // 10 iterations, fully unrolled
        CMPC(2 * p, eA, eB, eC)
        if (p + 1 < CPG / 2) LOADC(2 * p + 2, eA, eB, eC)
        CMPC(2 * p + 1, oA, oB, oC)
        if (p + 1 < CPG / 2) LOADC(2 * p + 3, oA, oB, oC)
    }
#undef LOADC
#undef CMPC

    size_t idx = (size_t)g * PLANE + (size_t)b * HW + (size_t)y * WW + x4;
    *(float4*)&conf_part[idx] = make_float4(conf[0], conf[1], conf[2], conf[3]);
    *(uchar4*)&cls_part[idx]  = make_uchar4((unsigned char)cls[0],
                                            (unsigned char)cls[1],
                                            (unsigned char)cls[2],
                                            (unsigned char)cls[3]);
}

// ---------------------------------------------------------------------------
// Kernel B: UNCHANGED from rounds 5-7 (controlled experiment: Dtotal=Dheat).
// ---------------------------------------------------------------------------
__global__ __launch_bounds__(NTHREADS, 1)
void select_nms(const float* __restrict__ conf_part,
                const unsigned char* __restrict__ cls_part,
                const float* __restrict__ wh,
                const float* __restrict__ offset,
                float* __restrict__ out) {
    const int b    = blockIdx.x;
    const int tid  = threadIdx.x;
    const int lane = tid & 63;
    const int wid  = tid >> 6;
    constexpr int VALS = HW / NTHREADS;   // 64

    __shared__ int wsum[4];
    __shared__ unsigned int sCnt;
    __shared__ unsigned long long keys[BUF];

    // ---- merge planar partials into registers (thresholded score bits) ----
    unsigned u[VALS];
#pragma unroll
    for (int k = 0; k < VALS; ++k) {
        size_t base = (size_t)b * HW + (k * NTHREADS + tid);
        float s0 = conf_part[base];
        float s1 = conf_part[PLANE + base];
        float s2 = conf_part[2 * PLANE + base];
        float s3 = conf_part[3 * PLANE + base];
        float best = fmaxf(fmaxf(s0, s1), fmaxf(s2, s3));
        u[k] = (best > SCORE_THR) ? __float_as_uint(best) : 0u;
    }

    auto blockCount = [&](unsigned T) -> int {
        int c = 0;
#pragma unroll
        for (int k = 0; k < VALS; ++k) c += (u[k] >= T);
        for (int o = 32; o > 0; o >>= 1) c += __shfl_down(c, o, 64);
        if (lane == 0) wsum[wid] = c;
        __syncthreads();
        int tot = wsum[0] + wsum[1] + wsum[2] + wsum[3];
        __syncthreads();
        return tot;
    };

    // ---- binary search on uint bits for the 100th-largest score ----
    unsigned V;
    {
        unsigned lo = MINT, hi = 0x3F800001u;   // scores in [0,1)
        int cl = blockCount(lo);
        if (cl < TOPK) {
            V = lo;
        } else {
            while (hi - lo > 1u) {
                unsigned mid = lo + ((hi - lo) >> 1);
                if (blockCount(mid) >= TOPK) lo = mid; else hi = mid;
            }
            V = lo;
        }
    }

    // ---- compact candidates (u >= V) ----
    if (tid == 0) sCnt = 0;
    for (int i = tid; i < BUF; i += NTHREADS) keys[i] = 0ull;
    __syncthreads();
#pragma unroll
    for (int k = 0; k < VALS; ++k) {
        if (u[k] >= V) {
            int i = k * NTHREADS + tid;
            unsigned pos = atomicAdd(&sCnt, 1u);
            if (pos < BUF)
                keys[pos] = ((unsigned long long)u[k] << 32) |
                            (unsigned)(HW - 1 - i);   // tie: lower index first
        }
    }
    __syncthreads();
    int cnt = (int)sCnt;
    if (cnt > BUF) cnt = BUF;

    // ---- bitonic sort (descending), size = next pow2 >= cnt ----
    int n = 1;
    while (n < cnt) n <<= 1;
    for (int k = 2; k <= n; k <<= 1) {
        for (int j = k >> 1; j > 0; j >>= 1) {
            for (int i = tid; i < n; i += NTHREADS) {
                int p = i ^ j;
                if (p > i) {
                    unsigned long long a = keys[i], bb2 = keys[p];
                    bool asc_seg = ((i & k) != 0);
                    bool sw = asc_seg ? (a > bb2) : (a < bb2);
                    if (sw) { keys[i] = bb2; keys[p] = a; }
                }
            }
            __syncthreads();
        }
    }

    // ---- gather top-100 ----
    __shared__ float bx[TOPK][4];
    __shared__ float barea[TOPK];
    __shared__ float bsc[TOPK];
    __shared__ int   bcls[TOPK];
    __shared__ int   keep[TOPK];

    if (tid < TOPK) {
        unsigned long long kk = keys[tid];
        float sc = __uint_as_float((unsigned)(kk >> 32));
        int   i  = HW - 1 - (int)(kk & 0xFFFFFFFFull);
        int   y  = (i >> 7) & 127;
        int   x  = i & 127;
        // merged class: group-ascending strict > == global first-index argmax
        size_t base0 = (size_t)b * HW + i;
        float bcf = conf_part[base0];
        int   bc  = (int)cls_part[base0];
#pragma unroll
        for (int gg = 1; gg < GG; ++gg) {
            float cf = conf_part[gg * PLANE + base0];
            if (cf > bcf) { bcf = cf; bc = (int)cls_part[gg * PLANE + base0]; }
        }

        size_t base = (size_t)b * 2 * HW + (size_t)y * WW + x;
        float ox = offset[base];
        float oy = offset[base + HW];
        float w  = wh[base];
        float hh = wh[base + HW];
        float cx = (float)x + ox;
        float cy = (float)y + oy;
        float x1 = (cx - w  * 0.5f) * (1.0f / 128.0f);
        float y1 = (cy - hh * 0.5f) * (1.0f / 128.0f);
        float x2 = (cx + w  * 0.5f) * (1.0f / 128.0f);
        float y2 = (cy + hh * 0.5f) * (1.0f / 128.0f);
        bx[tid][0] = x1; bx[tid][1] = y1; bx[tid][2] = x2; bx[tid][3] = y2;
        barea[tid] = (x2 - x1) * (y2 - y1);
        bsc[tid]   = sc;
        bcls[tid]  = bc;
        keep[tid]  = (sc > SCORE_THR) ? 1 : 0;
    }
    __syncthreads();

    // ---- greedy per-class NMS: single wave, shuffle broadcasts, 0 barriers --
    if (tid < 64) {
        const int A  = tid;
        const int Bq = tid + 64;
        float aX0 = bx[A][0], aY0 = bx[A][1], aX1 = bx[A][2], aY1 = bx[A][3];
        float aAr = barea[A]; int aC = bcls[A]; int kA = keep[A];
        float bX0 = 0, bY0 = 0, bX1 = 0, bY1 = 0, bAr = 0;
        int   bC = -1, kB = 0;
        if (Bq < TOPK) {
            bX0 = bx[Bq][0]; bY0 = bx[Bq][1]; bX1 = bx[Bq][2]; bY1 = bx[Bq][3];
            bAr = barea[Bq]; bC = bcls[Bq]; kB = keep[Bq];
        }
        for (int i = 0; i < TOPK; ++i) {
            int kv    = (i < 64) ? kA : kB;
            int alive = __shfl(kv, i & 63, 64);
            if (alive) {
                float iX0 = bx[i][0], iY0 = bx[i][1];
                float iX1 = bx[i][2], iY1 = bx[i][3];
                float iAr = barea[i]; int iC = bcls[i];
                if (A > i && aC == iC) {
                    float lx = fmaxf(aX0, iX0), ly = fmaxf(aY0, iY0);
                    float rx = fminf(aX1, iX1), ry = fminf(aY1, iY1);
                    float iw = fmaxf(rx - lx, 0.f), ih = fmaxf(ry - ly, 0.f);
                    float inter = iw * ih;
                    float iou = inter / (aAr + iAr - inter + 1e-9f);
                    if (iou > NMS_IOU) kA = 0;
                }
                if (Bq > i && Bq < TOPK && bC == iC) {
                    float lx = fmaxf(bX0, iX0), ly = fmaxf(bY0, iY0);
                    float rx = fminf(bX1, iX1), ry = fminf(bY1, iY1);
                    float iw = fmaxf(rx - lx, 0.f), ih = fmaxf(ry - ly, 0.f);
                    float inter = iw * ih;
                    float iou = inter / (bAr + iAr - inter + 1e-9f);
                    if (iou > NMS_IOU) kB = 0;
                }
            }
        }
        keep[A] = kA;
        if (Bq < TOPK) keep[Bq] = kB;
    }
    __syncthreads();

    // ---- output [B,100,6]; zero non-kept rows (d_out is poisoned) ----
    for (int t = tid; t < TOPK * 6; t += NTHREADS) {
        int j = t / 6, comp = t - j * 6;
        float v = 0.0f;
        if (keep[j]) {
            if (comp < 4)       v = bx[j][comp] * 512.0f;
            else if (comp == 4) v = bsc[j];
            else                v = (float)bcls[j];
        }
        out[(size_t)b * (TOPK * 6) + t] = v;
    }
}

extern "C" void kernel_launch(void* const* d_in, const int* in_sizes, int n_in,
                              void* d_out, int out_size, void* d_ws, size_t ws_size,
                              hipStream_t stream) {
    const float* hm     = (const float*)d_in[0];
    const float* wh     = (const float*)d_in[1];
    const float* offset = (const float*)d_in[2];
    float* out = (float*)d_out;

    float* confp = (float*)d_ws;                                 // 8 MB planar
    unsigned char* clsp = (unsigned char*)d_ws + GG * PLANE * 4; // 2 MB planar

    heat_reduce<<<BB * GG * 16, NTHREADS, 0, stream>>>(hm, confp, clsp);
    select_nms<<<BB, NTHREADS, 0, stream>>>(confp, clsp, wh, offset, out);
}

// Round 9
// 283.051 us; speedup vs baseline: 1.3100x; 1.3100x over previous
//
#include <hip/hip_runtime.h>
#include <hip/hip_bf16.h>
#include <stdint.h>

#define HH 128
#define WW 128
#define CC 80
#define HW (HH * WW)
#define BB 32
#define TOPK 100
#define NTHREADS 256
#define SCORE_THR 0.3f
#define NMS_IOU 0.3f
#define BUF 512
#define GG 4
#define PLANE ((size_t)BB * HW)
// smallest uint bit pattern with float > 0.3f  (bits(0.3f)=0x3E99999A)
#define MINT 0x3E99999Bu

// ---------------------------------------------------------------------------
// Kernel A: peak-NMS + per-group channel max/argmax. NO LDS, NO barriers.
// Grid: 32 b x 4 groups x 16 stripes = 2048 blocks, 256 thr.
// Round-9: rounds 7/8 showed 227 MB of scratch traffic REGARDLESS of array
// vs named registers -> cause is the 64-VGPR cap from launch_bounds(256,8)
// plus full-unroll load hoisting. Fix: launch_bounds(256,4) (128-VGPR cap)
// and #pragma unroll 2 (bounded hoist window). Even/odd named-register
// 2-slot pipeline retained: while computing channel pair p, pair p+1's six
// dwordx4 are in flight. Vertical-max-first pool: 2 shuffles/channel.
// Clamp pad == -inf pad for 3x3 max-pool. Partials PLANAR [G][B*HW].
// ---------------------------------------------------------------------------
__global__ __launch_bounds__(NTHREADS, 4)
void heat_reduce(const float* __restrict__ hm,
                 float* __restrict__ conf_part,
                 unsigned char* __restrict__ cls_part) {
    constexpr int CPG = CC / GG;              // 20 channels per group
    const int stripe = blockIdx.x & 15;
    const int g      = (blockIdx.x >> 4) & 3;
    const int b      = blockIdx.x >> 6;
    const int tid    = threadIdx.x;
    const int c31    = tid & 31;
    const int r      = tid >> 5;              // 0..7 row within stripe
    const int x4     = c31 << 2;              // 0,4,...,124
    const int y      = stripe * 8 + r;
    const int yM     = (y > 0) ? y - 1 : 0;
    const int yP     = (y < HH - 1) ? y + 1 : y;
    const bool leftClamp  = (c31 == 0);
    const bool rightClamp = (c31 == 31);
    const int c0     = g * CPG;

    const float* cbase = hm + (size_t)(b * CC + c0) * HW;
    const uint u0 = (uint)(yM * WW + x4);     // row above (clamped)
    const uint u1 = (uint)(y  * WW + x4);     // center row
    const uint u2 = (uint)(yP * WW + x4);     // row below (clamped)

    float conf[4] = {0.f, 0.f, 0.f, 0.f};
    int   cls[4]  = {c0, c0, c0, c0};

    float4 eA, eB, eC;                        // even-channel slot
    float4 oA, oB, oC;                        // odd-channel slot

#define LOADC(cc, rA, rB, rC)                                   \
    {                                                           \
        const float* cb_ = cbase + (size_t)(cc) * HW;           \
        rA = *(const float4*)(cb_ + u0);                        \
        rB = *(const float4*)(cb_ + u1);                        \
        rC = *(const float4*)(cb_ + u2);                        \
    }

#define CMPC(cc, rA, rB, rC)                                    \
    {                                                           \
        float vx = fmaxf(fmaxf(rA.x, rB.x), rC.x);              \
        float vy = fmaxf(fmaxf(rA.y, rB.y), rC.y);              \
        float vz = fmaxf(fmaxf(rA.z, rB.z), rC.z);              \
        float vw = fmaxf(fmaxf(rA.w, rB.w), rC.w);              \
        float le = __shfl_up(vw, 1, 64);                        \
        float re = __shfl_down(vx, 1, 64);                      \
        if (leftClamp)  le = vx;                                \
        if (rightClamp) re = vw;                                \
        float p0 = fmaxf(fmaxf(le, vx), vy);                    \
        float p1 = fmaxf(fmaxf(vx, vy), vz);                    \
        float p2 = fmaxf(fmaxf(vy, vz), vw);                    \
        float p3 = fmaxf(fmaxf(vz, vw), re);                    \
        const int c_ = c0 + (cc);                               \
        if ((rB.x == p0) && (rB.x > conf[0])) { conf[0] = rB.x; cls[0] = c_; } \
        if ((rB.y == p1) && (rB.y > conf[1])) { conf[1] = rB.y; cls[1] = c_; } \
        if ((rB.z == p2) && (rB.z > conf[2])) { conf[2] = rB.z; cls[2] = c_; } \
        if ((rB.w == p3) && (rB.w > conf[3])) { conf[3] = rB.w; cls[3] = c_; } \
    }

    LOADC(0, eA, eB, eC)
    LOADC(1, oA, oB, oC)
#pragma unroll 2
    for (int p = 0; p < CPG / 2; ++p) {       // 10 pair-iterations
        CMPC(2 * p, eA, eB, eC)
        if (p + 1 < CPG / 2) LOADC(2 * p + 2, eA, eB, eC)
        CMPC(2 * p + 1, oA, oB, oC)
        if (p + 1 < CPG / 2) LOADC(2 * p + 3, oA, oB, oC)
    }
#undef LOADC
#undef CMPC

    size_t idx = (size_t)g * PLANE + (size_t)b * HW + (size_t)y * WW + x4;
    *(float4*)&conf_part[idx] = make_float4(conf[0], conf[1], conf[2], conf[3]);
    *(uchar4*)&cls_part[idx]  = make_uchar4((unsigned char)cls[0],
                                            (unsigned char)cls[1],
                                            (unsigned char)cls[2],
                                            (unsigned char)cls[3]);
}

// ---------------------------------------------------------------------------
// Kernel B: UNCHANGED from rounds 5-8 (controlled experiment: Dtotal=Dheat).
// ---------------------------------------------------------------------------
__global__ __launch_bounds__(NTHREADS, 1)
void select_nms(const float* __restrict__ conf_part,
                const unsigned char* __restrict__ cls_part,
                const float* __restrict__ wh,
                const float* __restrict__ offset,
                float* __restrict__ out) {
    const int b    = blockIdx.x;
    const int tid  = threadIdx.x;
    const int lane = tid & 63;
    const int wid  = tid >> 6;
    constexpr int VALS = HW / NTHREADS;   // 64

    __shared__ int wsum[4];
    __shared__ unsigned int sCnt;
    __shared__ unsigned long long keys[BUF];

    // ---- merge planar partials into registers (thresholded score bits) ----
    unsigned u[VALS];
#pragma unroll
    for (int k = 0; k < VALS; ++k) {
        size_t base = (size_t)b * HW + (k * NTHREADS + tid);
        float s0 = conf_part[base];
        float s1 = conf_part[PLANE + base];
        float s2 = conf_part[2 * PLANE + base];
        float s3 = conf_part[3 * PLANE + base];
        float best = fmaxf(fmaxf(s0, s1), fmaxf(s2, s3));
        u[k] = (best > SCORE_THR) ? __float_as_uint(best) : 0u;
    }

    auto blockCount = [&](unsigned T) -> int {
        int c = 0;
#pragma unroll
        for (int k = 0; k < VALS; ++k) c += (u[k] >= T);
        for (int o = 32; o > 0; o >>= 1) c += __shfl_down(c, o, 64);
        if (lane == 0) wsum[wid] = c;
        __syncthreads();
        int tot = wsum[0] + wsum[1] + wsum[2] + wsum[3];
        __syncthreads();
        return tot;
    };

    // ---- binary search on uint bits for the 100th-largest score ----
    unsigned V;
    {
        unsigned lo = MINT, hi = 0x3F800001u;   // scores in [0,1)
        int cl = blockCount(lo);
        if (cl < TOPK) {
            V = lo;
        } else {
            while (hi - lo > 1u) {
                unsigned mid = lo + ((hi - lo) >> 1);
                if (blockCount(mid) >= TOPK) lo = mid; else hi = mid;
            }
            V = lo;
        }
    }

    // ---- compact candidates (u >= V) ----
    if (tid == 0) sCnt = 0;
    for (int i = tid; i < BUF; i += NTHREADS) keys[i] = 0ull;
    __syncthreads();
#pragma unroll
    for (int k = 0; k < VALS; ++k) {
        if (u[k] >= V) {
            int i = k * NTHREADS + tid;
            unsigned pos = atomicAdd(&sCnt, 1u);
            if (pos < BUF)
                keys[pos] = ((unsigned long long)u[k] << 32) |
                            (unsigned)(HW - 1 - i);   // tie: lower index first
        }
    }
    __syncthreads();
    int cnt = (int)sCnt;
    if (cnt > BUF) cnt = BUF;

    // ---- bitonic sort (descending), size = next pow2 >= cnt ----
    int n = 1;
    while (n < cnt) n <<= 1;
    for (int k = 2; k <= n; k <<= 1) {
        for (int j = k >> 1; j > 0; j >>= 1) {
            for (int i = tid; i < n; i += NTHREADS) {
                int p = i ^ j;
                if (p > i) {
                    unsigned long long a = keys[i], bb2 = keys[p];
                    bool asc_seg = ((i & k) != 0);
                    bool sw = asc_seg ? (a > bb2) : (a < bb2);
                    if (sw) { keys[i] = bb2; keys[p] = a; }
                }
            }
            __syncthreads();
        }
    }

    // ---- gather top-100 ----
    __shared__ float bx[TOPK][4];
    __shared__ float barea[TOPK];
    __shared__ float bsc[TOPK];
    __shared__ int   bcls[TOPK];
    __shared__ int   keep[TOPK];

    if (tid < TOPK) {
        unsigned long long kk = keys[tid];
        float sc = __uint_as_float((unsigned)(kk >> 32));
        int   i  = HW - 1 - (int)(kk & 0xFFFFFFFFull);
        int   y  = (i >> 7) & 127;
        int   x  = i & 127;
        // merged class: group-ascending strict > == global first-index argmax
        size_t base0 = (size_t)b * HW + i;
        float bcf = conf_part[base0];
        int   bc  = (int)cls_part[base0];
#pragma unroll
        for (int gg = 1; gg < GG; ++gg) {
            float cf = conf_part[gg * PLANE + base0];
            if (cf > bcf) { bcf = cf; bc = (int)cls_part[gg * PLANE + base0]; }
        }

        size_t base = (size_t)b * 2 * HW + (size_t)y * WW + x;
        float ox = offset[base];
        float oy = offset[base + HW];
        float w  = wh[base];
        float hh = wh[base + HW];
        float cx = (float)x + ox;
        float cy = (float)y + oy;
        float x1 = (cx - w  * 0.5f) * (1.0f / 128.0f);
        float y1 = (cy - hh * 0.5f) * (1.0f / 128.0f);
        float x2 = (cx + w  * 0.5f) * (1.0f / 128.0f);
        float y2 = (cy + hh * 0.5f) * (1.0f / 128.0f);
        bx[tid][0] = x1; bx[tid][1] = y1; bx[tid][2] = x2; bx[tid][3] = y2;
        barea[tid] = (x2 - x1) * (y2 - y1);
        bsc[tid]   = sc;
        bcls[tid]  = bc;
        keep[tid]  = (sc > SCORE_THR) ? 1 : 0;
    }
    __syncthreads();

    // ---- greedy per-class NMS: single wave, shuffle broadcasts, 0 barriers --
    if (tid < 64) {
        const int A  = tid;
        const int Bq = tid + 64;
        float aX0 = bx[A][0], aY0 = bx[A][1], aX1 = bx[A][2], aY1 = bx[A][3];
        float aAr = barea[A]; int aC = bcls[A]; int kA = keep[A];
        float bX0 = 0, bY0 = 0, bX1 = 0, bY1 = 0, bAr = 0;
        int   bC = -1, kB = 0;
        if (Bq < TOPK) {
            bX0 = bx[Bq][0]; bY0 = bx[Bq][1]; bX1 = bx[Bq][2]; bY1 = bx[Bq][3];
            bAr = barea[Bq]; bC = bcls[Bq]; kB = keep[Bq];
        }
        for (int i = 0; i < TOPK; ++i) {
            int kv    = (i < 64) ? kA : kB;
            int alive = __shfl(kv, i & 63, 64);
            if (alive) {
                float iX0 = bx[i][0], iY0 = bx[i][1];
                float iX1 = bx[i][2], iY1 = bx[i][3];
                float iAr = barea[i]; int iC = bcls[i];
                if (A > i && aC == iC) {
                    float lx = fmaxf(aX0, iX0), ly = fmaxf(aY0, iY0);
                    float rx = fminf(aX1, iX1), ry = fminf(aY1, iY1);
                    float iw = fmaxf(rx - lx, 0.f), ih = fmaxf(ry - ly, 0.f);
                    float inter = iw * ih;
                    float iou = inter / (aAr + iAr - inter + 1e-9f);
                    if (iou > NMS_IOU) kA = 0;
                }
                if (Bq > i && Bq < TOPK && bC == iC) {
                    float lx = fmaxf(bX0, iX0), ly = fmaxf(bY0, iY0);
                    float rx = fminf(bX1, iX1), ry = fminf(bY1, iY1);
                    float iw = fmaxf(rx - lx, 0.f), ih = fmaxf(ry - ly, 0.f);
                    float inter = iw * ih;
                    float iou = inter / (bAr + iAr - inter + 1e-9f);
                    if (iou > NMS_IOU) kB = 0;
                }
            }
        }
        keep[A] = kA;
        if (Bq < TOPK) keep[Bq] = kB;
    }
    __syncthreads();

    // ---- output [B,100,6]; zero non-kept rows (d_out is poisoned) ----
    for (int t = tid; t < TOPK * 6; t += NTHREADS) {
        int j = t / 6, comp = t - j * 6;
        float v = 0.0f;
        if (keep[j]) {
            if (comp < 4)       v = bx[j][comp] * 512.0f;
            else if (comp == 4) v = bsc[j];
            else                v = (float)bcls[j];
        }
        out[(size_t)b * (TOPK * 6) + t] = v;
    }
}

extern "C" void kernel_launch(void* const* d_in, const int* in_sizes, int n_in,
                              void* d_out, int out_size, void* d_ws, size_t ws_size,
                              hipStream_t stream) {
    const float* hm     = (const float*)d_in[0];
    const float* wh     = (const float*)d_in[1];
    const float* offset = (const float*)d_in[2];
    float* out = (float*)d_out;

    float* confp = (float*)d_ws;                                 // 8 MB planar
    unsigned char* clsp = (unsigned char*)d_ws + GG * PLANE * 4; // 2 MB planar

    heat_reduce<<<BB * GG * 16, NTHREADS, 0, stream>>>(hm, confp, clsp);
    select_nms<<<BB, NTHREADS, 0, stream>>>(confp, clsp, wh, offset, out);
}